// Round 3
// baseline (446.976 us; speedup 1.0000x reference)
//
#include <hip/hip_runtime.h>
#include <math.h>

#define BLOCK 256

__device__ __forceinline__ float waveRedF(float v) {
#pragma unroll
    for (int o = 32; o > 0; o >>= 1) v += __shfl_down(v, o, 64);
    return v;
}
__device__ __forceinline__ unsigned waveRedU(unsigned v) {
#pragma unroll
    for (int o = 32; o > 0; o >>= 1) v += __shfl_down(v, o, 64);
    return v;
}

// truth is exactly 0.0f or 1.0f, so BCE term = -log(t ? p : 1-p): one v_log_f32/elem.
__device__ __forceinline__ void elem(float p, float t, float& bce,
                                     unsigned& tp, unsigned& tn,
                                     unsigned& gp, unsigned& gn) {
    p = __builtin_isfinite(p) ? p : 0.0f;   // NaN/Inf -> 0 (matches reference)
    const bool tb = t > 0.0f;
    const bool pb = p > 0.5f;
    const float x = tb ? p : (1.0f - p);    // 1-p exact for p in [0.5,1] (Sterbenz)
    bce -= fmaxf(__logf(x), -100.0f);       // log(0) -> -inf -> clamp at -100
    gp += (unsigned)tb;
    gn += (unsigned)(!tb);
    tp += (unsigned)(pb & tb);
    tn += (unsigned)((!pb) & (!tb));
}

// One block per row; last-finishing block performs the final reduction
// (rocPRIM-style deterministic last-block-done, device-scope fences for XCDs).
__global__ __launch_bounds__(BLOCK) void rowKernel(
    const float* __restrict__ pred, const float* __restrict__ truth,
    const int* __restrict__ lengths, int B, int L,
    float* __restrict__ lossPart, unsigned* __restrict__ cntPart,
    unsigned* __restrict__ counter, float* __restrict__ out) {
    const int row = blockIdx.x;
    const int len = lengths[row];

    float bce = 0.0f;
    unsigned tp = 0, tn = 0, gp = 0, gn = 0;

    if (len > 0) {
        const float* pr = pred  + (size_t)row * L;
        const float* tr = truth + (size_t)row * L;
        const float4* pv = (const float4*)pr;
        const float4* tv = (const float4*)tr;
        const int nvec = len >> 2;
        for (int v = threadIdx.x; v < nvec; v += BLOCK) {
            float4 p4 = pv[v];
            float4 t4 = tv[v];
            elem(p4.x, t4.x, bce, tp, tn, gp, gn);
            elem(p4.y, t4.y, bce, tp, tn, gp, gn);
            elem(p4.z, t4.z, bce, tp, tn, gp, gn);
            elem(p4.w, t4.w, bce, tp, tn, gp, gn);
        }
        const int base = nvec << 2;
        const int tail = len - base;
        if ((int)threadIdx.x < tail) {
            elem(pr[base + threadIdx.x], tr[base + threadIdx.x], bce, tp, tn, gp, gn);
        }
    }

    bce = waveRedF(bce);
    tp = waveRedU(tp); tn = waveRedU(tn);
    gp = waveRedU(gp); gn = waveRedU(gn);

    __shared__ float sf[BLOCK / 64];
    __shared__ unsigned su[4][BLOCK / 64];
    __shared__ int isLast;
    const int wid  = threadIdx.x >> 6;
    const int lane = threadIdx.x & 63;
    if (lane == 0) {
        sf[wid] = bce;
        su[0][wid] = tp; su[1][wid] = tn; su[2][wid] = gp; su[3][wid] = gn;
    }
    __syncthreads();
    if (threadIdx.x == 0) {
        float bsum = 0.0f;
        unsigned ctp = 0, ctn = 0, cgp = 0, cgn = 0;
#pragma unroll
        for (int w = 0; w < BLOCK / 64; w++) {
            bsum += sf[w];
            ctp += su[0][w]; ctn += su[1][w]; cgp += su[2][w]; cgn += su[3][w];
        }
        lossPart[row]        = (len > 0) ? (bsum / (float)len) : 0.0f;
        cntPart[row]         = ctp;
        cntPart[B + row]     = ctn;
        cntPart[2 * B + row] = cgp;
        cntPart[3 * B + row] = cgn;
        __threadfence();                         // release partials (device scope)
        unsigned ticket = atomicAdd(counter, 1u);
        isLast = (ticket == (unsigned)(B - 1));
    }
    __syncthreads();
    if (!isLast) return;
    __threadfence();                             // acquire all blocks' partials

    // ---- final reduction, done by the last block only ----
    float ls = 0.0f;
    unsigned ftp = 0, ftn = 0, fgp = 0, fgn = 0;
    for (int i = threadIdx.x; i < B; i += BLOCK) {
        ls  += lossPart[i];
        ftp += cntPart[i];
        ftn += cntPart[B + i];
        fgp += cntPart[2 * B + i];
        fgn += cntPart[3 * B + i];
    }
    ls  = waveRedF(ls);
    ftp = waveRedU(ftp); ftn = waveRedU(ftn);
    fgp = waveRedU(fgp); fgn = waveRedU(fgn);

    __syncthreads();   // reuse sf/su safely
    if (lane == 0) {
        sf[wid] = ls;
        su[0][wid] = ftp; su[1][wid] = ftn; su[2][wid] = fgp; su[3][wid] = fgn;
    }
    __syncthreads();
    if (threadIdx.x == 0) {
        float lsum = 0.0f;
        unsigned ctp = 0, ctn = 0, cgp = 0, cgn = 0;
#pragma unroll
        for (int w = 0; w < BLOCK / 64; w++) {
            lsum += sf[w];
            ctp += su[0][w]; ctn += su[1][w]; cgp += su[2][w]; cgn += su[3][w];
        }
        if (cgp == 0) cgp = 1;
        if (cgn == 0) cgn = 1;
        out[0] = lsum / (float)B;
        out[1] = ((float)ctp / (float)cgp) * ((float)ctn / (float)cgn);
    }
}

extern "C" void kernel_launch(void* const* d_in, const int* in_sizes, int n_in,
                              void* d_out, int out_size, void* d_ws, size_t ws_size,
                              hipStream_t stream) {
    const float* pred    = (const float*)d_in[0];
    const float* truth   = (const float*)d_in[1];
    const int*   lengths = (const int*)d_in[2];
    const int B = in_sizes[2];
    const int L = in_sizes[0] / B;

    float*    lossPart = (float*)d_ws;
    unsigned* cntPart  = (unsigned*)((char*)d_ws + (size_t)B * sizeof(float));
    unsigned* counter  = (unsigned*)((char*)d_ws + (size_t)B * 5 * sizeof(unsigned));

    // zero the ticket counter (d_ws is poisoned 0xAA before every timed call)
    hipMemsetAsync(counter, 0, sizeof(unsigned), stream);

    rowKernel<<<B, BLOCK, 0, stream>>>(pred, truth, lengths, B, L,
                                       lossPart, cntPart, counter, (float*)d_out);
}

// Round 4
// 253.007 us; speedup vs baseline: 1.7667x; 1.7667x over previous
//
#include <hip/hip_runtime.h>
#include <math.h>

#define BLOCK 256

__device__ __forceinline__ float waveRedF(float v) {
#pragma unroll
    for (int o = 32; o > 0; o >>= 1) v += __shfl_down(v, o, 64);
    return v;
}
__device__ __forceinline__ unsigned waveRedU(unsigned v) {
#pragma unroll
    for (int o = 32; o > 0; o >>= 1) v += __shfl_down(v, o, 64);
    return v;
}

// truth is exactly 0.0f or 1.0f -> BCE term = -log(t ? p : 1-p): one v_log_f32/elem.
// gn is NOT tracked; derived as (sum of lengths) - gp in the reduce kernel.
__device__ __forceinline__ void elem(float p, float t, float& bce,
                                     unsigned& tp, unsigned& tn, unsigned& gp) {
    p = __builtin_isfinite(p) ? p : 0.0f;   // NaN/Inf -> 0 (matches reference)
    const bool tb = t > 0.5f;
    const bool pb = p > 0.5f;
    const float x = tb ? p : (1.0f - p);    // 1-p exact for p in [0.5,1] (Sterbenz)
    bce -= fmaxf(__logf(x), -100.0f);       // log(0) -> -inf -> clamp at -100
    gp += (unsigned)tb;
    tp += (unsigned)(pb & tb);
    tn += (unsigned)((!pb) & (!tb));
}

// Phase 1: one block per row. Writes lossPart[row] and one uint4 of counts
// unconditionally (slots overwrite the 0xAA poison; no memset, no atomics).
__global__ __launch_bounds__(BLOCK) void rowKernel(
    const float* __restrict__ pred, const float* __restrict__ truth,
    const int* __restrict__ lengths, int L,
    float* __restrict__ lossPart, uint4* __restrict__ cntPart) {
    const int row = blockIdx.x;
    const int len = lengths[row];

    float bce = 0.0f;
    unsigned tp = 0, tn = 0, gp = 0;

    if (len > 0) {
        const float* pr = pred  + (size_t)row * L;
        const float* tr = truth + (size_t)row * L;
        const float4* pv = (const float4*)pr;
        const float4* tv = (const float4*)tr;
        const int nvec = len >> 2;
        int v = threadIdx.x;
        // unroll 2: four 16B loads in flight per thread
        for (; v + BLOCK < nvec; v += 2 * BLOCK) {
            float4 p0 = pv[v];
            float4 t0 = tv[v];
            float4 p1 = pv[v + BLOCK];
            float4 t1 = tv[v + BLOCK];
            elem(p0.x, t0.x, bce, tp, tn, gp);
            elem(p0.y, t0.y, bce, tp, tn, gp);
            elem(p0.z, t0.z, bce, tp, tn, gp);
            elem(p0.w, t0.w, bce, tp, tn, gp);
            elem(p1.x, t1.x, bce, tp, tn, gp);
            elem(p1.y, t1.y, bce, tp, tn, gp);
            elem(p1.z, t1.z, bce, tp, tn, gp);
            elem(p1.w, t1.w, bce, tp, tn, gp);
        }
        if (v < nvec) {
            float4 p0 = pv[v];
            float4 t0 = tv[v];
            elem(p0.x, t0.x, bce, tp, tn, gp);
            elem(p0.y, t0.y, bce, tp, tn, gp);
            elem(p0.z, t0.z, bce, tp, tn, gp);
            elem(p0.w, t0.w, bce, tp, tn, gp);
        }
        const int base = nvec << 2;
        const int tail = len - base;
        if ((int)threadIdx.x < tail) {
            elem(pr[base + threadIdx.x], tr[base + threadIdx.x], bce, tp, tn, gp);
        }
    }

    bce = waveRedF(bce);
    tp = waveRedU(tp); tn = waveRedU(tn); gp = waveRedU(gp);

    __shared__ float sf[BLOCK / 64];
    __shared__ unsigned su[3][BLOCK / 64];
    const int wid  = threadIdx.x >> 6;
    const int lane = threadIdx.x & 63;
    if (lane == 0) {
        sf[wid] = bce;
        su[0][wid] = tp; su[1][wid] = tn; su[2][wid] = gp;
    }
    __syncthreads();
    if (threadIdx.x == 0) {
        float bsum = 0.0f;
        unsigned ctp = 0, ctn = 0, cgp = 0;
#pragma unroll
        for (int w = 0; w < BLOCK / 64; w++) {
            bsum += sf[w];
            ctp += su[0][w]; ctn += su[1][w]; cgp += su[2][w];
        }
        lossPart[row] = (len > 0) ? (bsum / (float)len) : 0.0f;
        cntPart[row]  = make_uint4(ctp, ctn, cgp, 0u);
    }
}

// Phase 2: single block reduces B rows (~84 KB) -> 2 scalars.
__global__ __launch_bounds__(BLOCK) void reduceKernel(
    const float* __restrict__ lossPart, const uint4* __restrict__ cntPart,
    const int* __restrict__ lengths, int B, float* __restrict__ out) {
    float ls = 0.0f;
    unsigned tp = 0, tn = 0, gp = 0, tot = 0;
    for (int i = threadIdx.x; i < B; i += BLOCK) {
        ls += lossPart[i];
        uint4 c = cntPart[i];
        tp += c.x; tn += c.y; gp += c.z;
        tot += (unsigned)lengths[i];
    }
    ls  = waveRedF(ls);
    tp  = waveRedU(tp); tn = waveRedU(tn);
    gp  = waveRedU(gp); tot = waveRedU(tot);

    __shared__ float sf[BLOCK / 64];
    __shared__ unsigned su[4][BLOCK / 64];
    const int wid  = threadIdx.x >> 6;
    const int lane = threadIdx.x & 63;
    if (lane == 0) {
        sf[wid] = ls;
        su[0][wid] = tp; su[1][wid] = tn; su[2][wid] = gp; su[3][wid] = tot;
    }
    __syncthreads();
    if (threadIdx.x == 0) {
        float lsum = 0.0f;
        unsigned ctp = 0, ctn = 0, cgp = 0, ctot = 0;
#pragma unroll
        for (int w = 0; w < BLOCK / 64; w++) {
            lsum += sf[w];
            ctp += su[0][w]; ctn += su[1][w]; cgp += su[2][w]; ctot += su[3][w];
        }
        unsigned cgn = ctot - cgp;   // (mask & ~targ).sum()
        if (cgp == 0) cgp = 1;
        if (cgn == 0) cgn = 1;
        out[0] = lsum / (float)B;
        out[1] = ((float)ctp / (float)cgp) * ((float)ctn / (float)cgn);
    }
}

extern "C" void kernel_launch(void* const* d_in, const int* in_sizes, int n_in,
                              void* d_out, int out_size, void* d_ws, size_t ws_size,
                              hipStream_t stream) {
    const float* pred    = (const float*)d_in[0];
    const float* truth   = (const float*)d_in[1];
    const int*   lengths = (const int*)d_in[2];
    const int B = in_sizes[2];
    const int L = in_sizes[0] / B;

    float* lossPart = (float*)d_ws;
    uint4* cntPart  = (uint4*)((char*)d_ws + (size_t)B * sizeof(float) + 15 -
                               (((size_t)B * sizeof(float) + 15) & 15) +
                               ((((size_t)B * sizeof(float)) + 15) & ~(size_t)15) -
                               ((size_t)B * sizeof(float) + 15 - (((size_t)B * sizeof(float) + 15) & 15)));
    // (simplify: B*4 bytes is already 16-aligned for B=4096; compute plainly)
    cntPart = (uint4*)((char*)d_ws + ((((size_t)B * sizeof(float)) + 15) & ~(size_t)15));

    rowKernel<<<B, BLOCK, 0, stream>>>(pred, truth, lengths, L, lossPart, cntPart);
    reduceKernel<<<1, BLOCK, 0, stream>>>(lossPart, cntPart, lengths, B, (float*)d_out);
}